// Round 11
// baseline (88.673 us; speedup 1.0000x reference)
//
#include <hip/hip_runtime.h>
#include <math.h>

#define Bb   64
#define Nn   8192
#define Dd   64
#define Cc   256
#define INn  128
#define CTRL 192
#define OUTW 320
#define EPSF 1e-8f
#define BN   (Bb*Nn)

typedef float f4 __attribute__((ext_vector_type(4)));
typedef float f2 __attribute__((ext_vector_type(2)));

// ---------------- workspace layout (floats) ----------------
#define OFF_XE  0                     // packed {xw, e2} per row           [BN*2]
#define OFF_P4  (2*BN)                // packed per-row {dr,c5,nq,e1}      [BN*4]
#define OFF_WPW (6*BN)                // NORMALIZED wpow_w                 [BN]
#define OFF_WPR (7*BN)                // NORMALIZED wpow_r                 [BN]
#define OFF_PT  (8*BN)                // read-vec partials                 [2048*64]
#define OFF_MS  (OFF_PT + 131072)     // W-side online {M,S} per p1 block  [4096*2]
#define OFF_KW  (OFF_MS + 8192)       // k_w                               [B*D]
#define OFF_KR  (OFF_KW + Bb*Dd)      // k_r                               [B*D]
#define OFF_ER  (OFF_KR + Bb*Dd)      // erase (post-sigmoid)              [B*D]
#define OFF_AD  (OFF_ER + Bb*Dd)      // add (post-tanh)                   [B*D]
#define OFF_SC  (OFF_AD + Bb*Dd)      // per-b scalars                     [B*16]
// per-b scalars: 0..3 beta_w,g_w,gam_w,knorm_w | 4..7 beta_r,g_r,gam_r,knorm_r
//                8..10 s_w | 11 AK=a.k_r | 12..14 s_r | 15 A2=|a|^2

__device__ __forceinline__ float softplusf(float x) {
    return (x > 20.f) ? x : log1pf(__expf(x));
}
__device__ __forceinline__ float sigmoidf(float x) {
    return 1.f / (1.f + __expf(-x));
}
__device__ __forceinline__ void msCombine(float& m, float& s, float m2, float s2) {
    const float mn = fmaxf(m, m2);
    s = s * __expf(m - mn) + s2 * __expf(m2 - mn);
    m = mn;
}

// ---- block reductions for 1024 threads (16 waves), red[16] LDS ----
__device__ __forceinline__ float blockSum1024(float v, float* red) {
    #pragma unroll
    for (int m = 32; m >= 1; m >>= 1) v += __shfl_xor(v, m);
    __syncthreads();
    if ((threadIdx.x & 63) == 0) red[threadIdx.x >> 6] = v;
    __syncthreads();
    float s = 0.f;
    #pragma unroll
    for (int i = 0; i < 16; ++i) s += red[i];
    return s;
}
__device__ __forceinline__ float blockMax1024(float v, float* red) {
    #pragma unroll
    for (int m = 32; m >= 1; m >>= 1) v = fmaxf(v, __shfl_xor(v, m));
    __syncthreads();
    if ((threadIdx.x & 63) == 0) red[threadIdx.x >> 6] = v;
    __syncthreads();
    float s = -1e30f;
    #pragma unroll
    for (int i = 0; i < 16; ++i) s = fmaxf(s, red[i]);
    return s;
}

struct SetupArgs {
    const float *x, *prv, *Wc, *bc;
    const float *Wk_r, *bk_r, *Wb_r, *bb_r, *Wg_r, *bg_r, *Ws_r, *bs_r, *Wgam_r, *bgam_r;
    const float *Wk_w, *bk_w, *Wb_w, *bb_w, *Wg_w, *bg_w, *Ws_w, *bs_w, *Wgam_w, *bgam_w;
    const float *We_w, *be_w, *Wa_w, *ba_w;
    float *ws, *out;
};

// one block per batch: controller GEMM + projections + batched scalar reductions
__global__ __launch_bounds__(256) void k_setup(SetupArgs a) {
    __shared__ float ci[CTRL];
    __shared__ float h[Cc];
    __shared__ alignas(16) float kbuf[128];
    __shared__ alignas(16) float abuf[64];
    __shared__ float red[4][16];
    __shared__ float sums[16];
    const int b = blockIdx.x, t = threadIdx.x;

    if (t < INn)       ci[t] = a.x[b * INn + t];
    else if (t < CTRL) ci[t] = a.prv[b * Dd + (t - INn)];
    __syncthreads();

    float acc = a.bc[t];
    #pragma unroll 16
    for (int i = 0; i < CTRL; ++i) acc += ci[i] * a.Wc[i * Cc + t];
    const float hv = fmaxf(acc, 0.f);
    h[t] = hv;
    a.out[b * OUTW + t] = hv;
    __syncthreads();

    {
        const int job = t >> 6, d = t & 63;
        const float* W  = (job == 0) ? a.Wk_w : (job == 1) ? a.Wk_r : (job == 2) ? a.We_w : a.Wa_w;
        const float* bs = (job == 0) ? a.bk_w : (job == 1) ? a.bk_r : (job == 2) ? a.be_w : a.ba_w;
        float p = bs[d];
        #pragma unroll 16
        for (int c = 0; c < Cc; ++c) p += h[c] * W[c * Dd + d];
        if (job == 0)      { a.ws[OFF_KW + b * Dd + d] = p; kbuf[d] = p; }
        else if (job == 1) { a.ws[OFF_KR + b * Dd + d] = p; kbuf[64 + d] = p; }
        else if (job == 2) { a.ws[OFF_ER + b * Dd + d] = sigmoidf(p); }
        else               { const float ad = tanhf(p); a.ws[OFF_AD + b * Dd + d] = ad; abuf[d] = ad; }
    }
    __syncthreads();

    float v[16];
    v[0] = hv * a.Wb_w[t];  v[1] = hv * a.Wg_w[t];  v[2] = hv * a.Wgam_w[t];
    v[3] = hv * a.Ws_w[t * 3 + 0]; v[4] = hv * a.Ws_w[t * 3 + 1]; v[5] = hv * a.Ws_w[t * 3 + 2];
    v[6] = hv * a.Wb_r[t];  v[7] = hv * a.Wg_r[t];  v[8] = hv * a.Wgam_r[t];
    v[9] = hv * a.Ws_r[t * 3 + 0]; v[10] = hv * a.Ws_r[t * 3 + 1]; v[11] = hv * a.Ws_r[t * 3 + 2];
    v[12] = (t < 64) ? kbuf[t] * kbuf[t] : 0.f;
    v[13] = (t >= 64 && t < 128) ? kbuf[t] * kbuf[t] : 0.f;
    v[14] = (t < 64) ? abuf[t] * kbuf[64 + t] : 0.f;
    v[15] = (t < 64) ? abuf[t] * abuf[t] : 0.f;
    #pragma unroll
    for (int k = 0; k < 16; ++k) {
        #pragma unroll
        for (int m = 32; m >= 1; m >>= 1) v[k] += __shfl_xor(v[k], m);
    }
    if ((t & 63) == 0) {
        #pragma unroll
        for (int k = 0; k < 16; ++k) red[t >> 6][k] = v[k];
    }
    __syncthreads();
    if (t < 16) sums[t] = red[0][t] + red[1][t] + red[2][t] + red[3][t];
    __syncthreads();

    if (t == 0) {
        float* sc = a.ws + OFF_SC + b * 16;
        sc[0] = softplusf(sums[0] + a.bb_w[0]);
        sc[1] = sigmoidf(sums[1] + a.bg_w[0]);
        sc[2] = softplusf(sums[2] + a.bgam_w[0]) + 1.f;
        sc[3] = sqrtf(sums[12]);
        sc[4] = softplusf(sums[6] + a.bb_r[0]);
        sc[5] = sigmoidf(sums[7] + a.bg_r[0]);
        sc[6] = softplusf(sums[8] + a.bgam_r[0]) + 1.f;
        sc[7] = sqrtf(sums[13]);
        {
            const float v0 = sums[3] + a.bs_w[0], v1 = sums[4] + a.bs_w[1], v2 = sums[5] + a.bs_w[2];
            const float m = fmaxf(fmaxf(v0, v1), v2);
            const float e0 = __expf(v0 - m), e1 = __expf(v1 - m), e2 = __expf(v2 - m);
            const float s = e0 + e1 + e2;
            sc[8] = e0 / s; sc[9] = e1 / s; sc[10] = e2 / s;
        }
        sc[11] = sums[14];
        {
            const float v0 = sums[9] + a.bs_r[0], v1 = sums[10] + a.bs_r[1], v2 = sums[11] + a.bs_r[2];
            const float m = fmaxf(fmaxf(v0, v1), v2);
            const float e0 = __expf(v0 - m), e1 = __expf(v1 - m), e2 = __expf(v2 - m);
            const float s = e0 + e1 + e2;
            sc[12] = e0 / s; sc[13] = e1 / s; sc[14] = e2 / s;
        }
        sc[15] = sums[15];
    }
}

// streaming pass: 4096 blocks, one 32-row tile per wave.
// mem loads NORMAL (allocate L3 for k_read); intermediate stores NONTEMPORAL
// (consumers are on other XCDs; don't pollute this XCD's L2).
__global__ __launch_bounds__(256) void k_pass1(const float* __restrict__ mem,
                                               float* __restrict__ ws) {
    __shared__ float tr[4][32 * 49];
    __shared__ float wm[4], wsum[4];
    const int t = threadIdx.x;
    const int wv = t >> 6, lane = t & 63;
    const int cg = lane & 7;
    const int rr = lane >> 3;
    const int tile = (blockIdx.x << 2) + wv;
    const int rowbase = tile << 5;
    const int b = rowbase >> 13;
    const int cb = cg << 3;

    const float4 kwA = *(const float4*)(ws + OFF_KW + (b << 6) + cb);
    const float4 kwB = *(const float4*)(ws + OFF_KW + (b << 6) + cb + 4);
    const float4 krA = *(const float4*)(ws + OFF_KR + (b << 6) + cb);
    const float4 krB = *(const float4*)(ws + OFF_KR + (b << 6) + cb + 4);
    const float4 evA = *(const float4*)(ws + OFF_ER + (b << 6) + cb);
    const float4 evB = *(const float4*)(ws + OFF_ER + (b << 6) + cb + 4);
    const float4 avA = *(const float4*)(ws + OFF_AD + (b << 6) + cb);
    const float4 avB = *(const float4*)(ws + OFF_AD + (b << 6) + cb + 4);
    const float beta = ws[OFF_SC + b * 16 + 0];
    const float kn   = ws[OFF_SC + b * 16 + 3];

    float acc[4][6];
    #pragma unroll
    for (int s = 0; s < 4; ++s) {
        const int row = rowbase + (s << 3) + rr;
        const float* mp = mem + ((size_t)row << 6) + cb;
        const float4 m0 = *(const float4*)(mp);
        const float4 m1 = *(const float4*)(mp + 4);
        float dw = 0.f, dr = 0.f, nq = 0.f, e1 = 0.f, e2 = 0.f, c5 = 0.f;
        #define ACC(mv, kwv, krv, evv, avv) { \
            const float me = (mv) * (evv); \
            dw = fmaf((mv), (kwv), dw); \
            dr = fmaf((mv), (krv), dr); \
            nq = fmaf((mv), (mv), nq); \
            e1 = fmaf((mv), (avv) - me, e1); \
            e2 = fmaf(me, fmaf(-2.f, (avv), me), e2); \
            c5 = fmaf(me, (krv), c5); }
        ACC(m0.x, kwA.x, krA.x, evA.x, avA.x)
        ACC(m0.y, kwA.y, krA.y, evA.y, avA.y)
        ACC(m0.z, kwA.z, krA.z, evA.z, avA.z)
        ACC(m0.w, kwA.w, krA.w, evA.w, avA.w)
        ACC(m1.x, kwB.x, krB.x, evB.x, avB.x)
        ACC(m1.y, kwB.y, krB.y, evB.y, avB.y)
        ACC(m1.z, kwB.z, krB.z, evB.z, avB.z)
        ACC(m1.w, kwB.w, krB.w, evB.w, avB.w)
        #undef ACC
        acc[s][0] = dw; acc[s][1] = dr; acc[s][2] = nq;
        acc[s][3] = e1; acc[s][4] = e2; acc[s][5] = c5;
    }

    float* T = tr[wv];
    #pragma unroll
    for (int s = 0; s < 4; ++s) {
        #pragma unroll
        for (int v = 0; v < 6; ++v)
            T[((s << 3) + rr) * 49 + cg * 6 + v] = acc[s][v];
    }
    __syncthreads();

    const int rd = lane & 31;
    const int gb = (lane >> 5) << 2;
    float dw = 0.f, dr = 0.f, nq = 0.f, e1 = 0.f, e2 = 0.f, c5 = 0.f;
    #pragma unroll
    for (int g = 0; g < 4; ++g) {
        const float* p = T + rd * 49 + (gb + g) * 6;
        dw += p[0]; dr += p[1]; nq += p[2];
        e1 += p[3]; e2 += p[4]; c5 += p[5];
    }
    dw += __shfl_xor(dw, 32); dr += __shfl_xor(dr, 32); nq += __shfl_xor(nq, 32);
    e1 += __shfl_xor(e1, 32); e2 += __shfl_xor(e2, 32); c5 += __shfl_xor(c5, 32);

    const int row = rowbase + rd;
    const float xw = beta * dw / (sqrtf(nq) * kn + EPSF);
    if (lane < 32) {
        f4 p4v; p4v.x = dr; p4v.y = c5; p4v.z = nq; p4v.w = e1;
        __builtin_nontemporal_store(p4v, (f4*)(ws + OFF_P4 + ((size_t)row << 2)));
        f2 xe; xe.x = xw; xe.y = e2;
        __builtin_nontemporal_store(xe, (f2*)(ws + OFF_XE + ((size_t)row << 1)));
    }

    float om = xw, os = 1.f;
    #pragma unroll
    for (int mk = 1; mk <= 32; mk <<= 1) {
        const float m2 = __shfl_xor(om, mk), s2 = __shfl_xor(os, mk);
        msCombine(om, os, m2, s2);
    }
    if (lane == 0) { wm[wv] = om; wsum[wv] = os; }
    __syncthreads();
    if (t == 0) {
        float M = wm[0], S = wsum[0];
        msCombine(M, S, wm[1], wsum[1]);
        msCombine(M, S, wm[2], wsum[2]);
        msCombine(M, S, wm[3], wsum[3]);
        ws[OFF_MS + (blockIdx.x << 1)]     = M;
        ws[OFF_MS + (blockIdx.x << 1) + 1] = S * 0.5f;
    }
}

// fused W+R addressing: one block (1024 thr) per batch; thread t owns rows [8t,8t+8).
// Stores NORMALIZED WPW / WPR (nontemporal: consumed by k_read on other XCDs).
__global__ __launch_bounds__(1024, 4) void k_addrBoth(float* __restrict__ ws,
                                                      const float* __restrict__ prevw_w,
                                                      const float* __restrict__ prevw_r) {
    __shared__ float buf[Nn];
    __shared__ float red[16];
    __shared__ float sMS[2];
    const int b = blockIdx.x, t = threadIdx.x;
    const int bN = b * Nn;
    const int base = t << 3;
    const float* sc = ws + OFF_SC + b * 16;
    const float g_w = sc[1], gam_w = sc[2];
    const float s0w = sc[8], s1w = sc[9], s2w = sc[10];
    const float beta_r = sc[4], g_r = sc[5], gam_r = sc[6], kn_r = sc[7];
    const float AK = sc[11], A2 = sc[15];
    const float s0r = sc[12], s1r = sc[13], s2r = sc[14];

    // combine the 64 per-pass1-block {M,S} pairs of this batch
    if (t < 64) {
        float m = ws[OFF_MS + ((b * 64 + t) << 1)];
        float s = ws[OFF_MS + ((b * 64 + t) << 1) + 1];
        #pragma unroll
        for (int mk = 1; mk <= 32; mk <<= 1) {
            const float m2 = __shfl_xor(m, mk), s2 = __shfl_xor(s, mk);
            msCombine(m, s, m2, s2);
        }
        if (t == 0) { sMS[0] = m; sMS[1] = 1.f / s; }
    }

    // ---- prefetch all per-row data (hides latency under W side) ----
    // XE packed {xw,e2}: 8 rows = 4 float4s
    const float4 xeA = *(const float4*)(ws + OFF_XE + ((size_t)(bN + base) << 1));
    const float4 xeB = *(const float4*)(ws + OFF_XE + ((size_t)(bN + base) << 1) + 4);
    const float4 xeC = *(const float4*)(ws + OFF_XE + ((size_t)(bN + base) << 1) + 8);
    const float4 xeD = *(const float4*)(ws + OFF_XE + ((size_t)(bN + base) << 1) + 12);
    const float4 pw0 = *(const float4*)(prevw_w + bN + base);
    const float4 pw1 = *(const float4*)(prevw_w + bN + base + 4);
    float4 p4[8];
    #pragma unroll
    for (int i = 0; i < 8; ++i)
        p4[i] = *(const float4*)(ws + OFF_P4 + ((size_t)(bN + base + i) << 2));
    const float4 pr0 = *(const float4*)(prevw_r + bN + base);
    const float4 pr1 = *(const float4*)(prevw_r + bN + base + 4);
    __syncthreads();           // sMS ready
    const float M = sMS[0], invS = sMS[1];

    // ---------- W side ----------
    float xs[8] = {xeA.x, xeA.z, xeB.x, xeB.z, xeC.x, xeC.z, xeD.x, xeD.z};
    const float e2a[8] = {xeA.y, xeA.w, xeB.y, xeB.w, xeC.y, xeC.w, xeD.y, xeD.w};
    float pw[8] = {pw0.x, pw0.y, pw0.z, pw0.w, pw1.x, pw1.y, pw1.z, pw1.w};
    #pragma unroll
    for (int i = 0; i < 8; ++i)
        buf[base + i] = g_w * __expf(xs[i] - M) * invS + (1.f - g_w) * pw[i];
    __syncthreads();
    {
        float nb[10];
        nb[0] = buf[(base + Nn - 1) & (Nn - 1)];
        #pragma unroll
        for (int i = 0; i < 8; ++i) nb[i + 1] = buf[base + i];
        nb[9] = buf[(base + 8) & (Nn - 1)];
        float lps = 0.f;
        #pragma unroll
        for (int i = 0; i < 8; ++i) {
            const float wsv = s0w * nb[i + 2] + s1w * nb[i + 1] + s2w * nb[i];
            const float wp = __expf(gam_w * __logf(wsv));
            xs[i] = wp; lps += wp;
        }
        const float PS = blockSum1024(lps, red);
        const float pinv = 1.f / (PS + EPSF);
        #pragma unroll
        for (int i = 0; i < 8; ++i) xs[i] *= pinv;     // normalized ww
    }
    {
        f4 w0, w1;
        w0.x = xs[0]; w0.y = xs[1]; w0.z = xs[2]; w0.w = xs[3];
        w1.x = xs[4]; w1.y = xs[5]; w1.z = xs[6]; w1.w = xs[7];
        __builtin_nontemporal_store(w0, (f4*)(ws + OFF_WPW + bN + base));
        __builtin_nontemporal_store(w1, (f4*)(ws + OFF_WPW + bN + base + 4));
    }

    // ---------- R side ----------
    float lmax = -1e30f;
    #pragma unroll
    for (int i = 0; i < 8; ++i) {
        const float w = xs[i];
        const float d = p4[i].x + w * (AK - p4[i].y);              // dr, c5
        float qq = p4[i].z + 2.f * w * p4[i].w + w * w * (e2a[i] + A2);  // nq, e1
        qq = fmaxf(qq, 0.f);
        const float x = beta_r * d / (sqrtf(qq) * kn_r + EPSF);
        xs[i] = x; lmax = fmaxf(lmax, x);
    }
    const float Mr = blockMax1024(lmax, red);
    float lsr = 0.f;
    #pragma unroll
    for (int i = 0; i < 8; ++i) { const float e = __expf(xs[i] - Mr); xs[i] = e; lsr += e; }
    const float Sr = blockSum1024(lsr, red);
    const float srinv = 1.f / Sr;
    const float prv8[8] = {pr0.x, pr0.y, pr0.z, pr0.w, pr1.x, pr1.y, pr1.z, pr1.w};
    __syncthreads();            // all W-side buf reads complete
    #pragma unroll
    for (int i = 0; i < 8; ++i)
        buf[base + i] = g_r * xs[i] * srinv + (1.f - g_r) * prv8[i];
    __syncthreads();
    {
        float nb[10];
        nb[0] = buf[(base + Nn - 1) & (Nn - 1)];
        #pragma unroll
        for (int i = 0; i < 8; ++i) nb[i + 1] = buf[base + i];
        nb[9] = buf[(base + 8) & (Nn - 1)];
        float lpr = 0.f;
        #pragma unroll
        for (int i = 0; i < 8; ++i) {
            const float wsv = s0r * nb[i + 2] + s1r * nb[i + 1] + s2r * nb[i];
            const float wp = __expf(gam_r * __logf(wsv));
            xs[i] = wp; lpr += wp;
        }
        const float PSr = blockSum1024(lpr, red);
        const float prinv = 1.f / (PSr + EPSF);
        f4 w0, w1;
        w0.x = xs[0] * prinv; w0.y = xs[1] * prinv; w0.z = xs[2] * prinv; w0.w = xs[3] * prinv;
        w1.x = xs[4] * prinv; w1.y = xs[5] * prinv; w1.z = xs[6] * prinv; w1.w = xs[7] * prinv;
        __builtin_nontemporal_store(w0, (f4*)(ws + OFF_WPR + bN + base));
        __builtin_nontemporal_store(w1, (f4*)(ws + OFF_WPR + bN + base + 4));
    }
}

// read-vector partials: recompute new_mem on the fly. mem loads NONTEMPORAL
// (last consumer; don't thrash L2 for the WPW/WPR loads).
__global__ __launch_bounds__(256) void k_read(const float* __restrict__ mem,
                                              float* __restrict__ ws) {
    __shared__ float lds[4 * 64];
    const int b = blockIdx.x >> 5;
    const int chunk = blockIdx.x & 31;
    const int t = threadIdx.x;
    const int lane = t & 63, wv = t >> 6;
    const int q = lane & 15, r = lane >> 4;

    const float4 evv = *(const float4*)(ws + OFF_ER + (b << 6) + (q << 2));
    const float4 avv = *(const float4*)(ws + OFF_AD + (b << 6) + (q << 2));
    float a0 = 0.f, a1 = 0.f, a2 = 0.f, a3 = 0.f;
    const int base_n = chunk << 8;
    #pragma unroll 4
    for (int gi = wv; gi < 64; gi += 4) {
        const int n = base_n + (gi << 2) + r;
        const int row = b * Nn + n;
        const f4 mv = __builtin_nontemporal_load((const f4*)(mem + ((size_t)row << 6) + (q << 2)));
        const float w   = ws[OFF_WPW + row];
        const float wrv = ws[OFF_WPR + row];
        a0 = fmaf((mv.x * (1.f - w * evv.x) + w * avv.x), wrv, a0);
        a1 = fmaf((mv.y * (1.f - w * evv.y) + w * avv.y), wrv, a1);
        a2 = fmaf((mv.z * (1.f - w * evv.z) + w * avv.z), wrv, a2);
        a3 = fmaf((mv.w * (1.f - w * evv.w) + w * avv.w), wrv, a3);
    }
    #pragma unroll
    for (int m = 16; m <= 32; m <<= 1) {
        a0 += __shfl_xor(a0, m); a1 += __shfl_xor(a1, m);
        a2 += __shfl_xor(a2, m); a3 += __shfl_xor(a3, m);
    }
    if (r == 0) {
        lds[wv * 64 + q * 4 + 0] = a0; lds[wv * 64 + q * 4 + 1] = a1;
        lds[wv * 64 + q * 4 + 2] = a2; lds[wv * 64 + q * 4 + 3] = a3;
    }
    __syncthreads();
    if (t < 64) {
        ws[OFF_PT + blockIdx.x * 64 + t] = lds[t] + lds[64 + t] + lds[128 + t] + lds[192 + t];
    }
}

__global__ __launch_bounds__(64) void k_reduce(const float* __restrict__ ws,
                                               float* __restrict__ out) {
    const int b = blockIdx.x, d = threadIdx.x;
    float s = 0.f;
    #pragma unroll
    for (int i = 0; i < 32; ++i) s += ws[OFF_PT + ((b << 5) + i) * 64 + d];
    out[b * OUTW + 256 + d] = s;
}

extern "C" void kernel_launch(void* const* d_in, const int* in_sizes, int n_in,
                              void* d_out, int out_size, void* d_ws, size_t ws_size,
                              hipStream_t stream) {
    const float* x      = (const float*)d_in[0];
    const float* mem    = (const float*)d_in[1];
    const float* prw_r  = (const float*)d_in[2];
    const float* prw_w  = (const float*)d_in[3];
    const float* prv    = (const float*)d_in[4];

    float* ws  = (float*)d_ws;
    float* out = (float*)d_out;

    SetupArgs a;
    a.x = x; a.prv = prv;
    a.Wc = (const float*)d_in[5];  a.bc = (const float*)d_in[6];
    a.Wk_r = (const float*)d_in[7];  a.bk_r = (const float*)d_in[8];
    a.Wb_r = (const float*)d_in[9];  a.bb_r = (const float*)d_in[10];
    a.Wg_r = (const float*)d_in[11]; a.bg_r = (const float*)d_in[12];
    a.Ws_r = (const float*)d_in[13]; a.bs_r = (const float*)d_in[14];
    a.Wgam_r = (const float*)d_in[15]; a.bgam_r = (const float*)d_in[16];
    a.Wk_w = (const float*)d_in[17]; a.bk_w = (const float*)d_in[18];
    a.Wb_w = (const float*)d_in[19]; a.bb_w = (const float*)d_in[20];
    a.Wg_w = (const float*)d_in[21]; a.bg_w = (const float*)d_in[22];
    a.Ws_w = (const float*)d_in[23]; a.bs_w = (const float*)d_in[24];
    a.Wgam_w = (const float*)d_in[25]; a.bgam_w = (const float*)d_in[26];
    a.We_w = (const float*)d_in[27]; a.be_w = (const float*)d_in[28];
    a.Wa_w = (const float*)d_in[29]; a.ba_w = (const float*)d_in[30];
    a.ws = ws; a.out = out;

    k_setup   <<<Bb,   256,  0, stream>>>(a);
    k_pass1   <<<4096, 256,  0, stream>>>(mem, ws);
    k_addrBoth<<<Bb,   1024, 0, stream>>>(ws, prw_w, prw_r);
    k_read    <<<2048, 256,  0, stream>>>(mem, ws);
    k_reduce  <<<Bb,   64,   0, stream>>>(ws, out);
}

// Round 12
// 82.212 us; speedup vs baseline: 1.0786x; 1.0786x over previous
//
#include <hip/hip_runtime.h>
#include <math.h>

#define Bb   64
#define Nn   8192
#define Dd   64
#define Cc   256
#define INn  128
#define CTRL 192
#define OUTW 320
#define EPSF 1e-8f
#define BN   (Bb*Nn)

// ---------------- workspace layout (floats) ----------------
#define OFF_XW  0                     // x_w = beta*sim (dense)            [BN]
#define OFF_P4  BN                    // packed per-row {dr,c5,nq,e1}      [BN*4]
#define OFF_E2  (5*BN)                // e2                                [BN]
#define OFF_WPW (6*BN)                // NORMALIZED wpow_w                 [BN]
#define OFF_WPR (7*BN)                // NORMALIZED wpow_r                 [BN]
#define OFF_PT  (8*BN)                // read-vec partials                 [2048*64]
#define OFF_MS  (OFF_PT + 131072)     // W-side online {M,S} per p1 block  [4096*2]
#define OFF_KW  (OFF_MS + 8192)       // k_w                               [B*D]
#define OFF_KR  (OFF_KW + Bb*Dd)      // k_r                               [B*D]
#define OFF_ER  (OFF_KR + Bb*Dd)      // erase (post-sigmoid)              [B*D]
#define OFF_AD  (OFF_ER + Bb*Dd)      // add (post-tanh)                   [B*D]
#define OFF_SC  (OFF_AD + Bb*Dd)      // per-b scalars                     [B*16]
// per-b scalars: 0..3 beta_w,g_w,gam_w,knorm_w | 4..7 beta_r,g_r,gam_r,knorm_r
//                8..10 s_w | 11 AK=a.k_r | 12..14 s_r | 15 A2=|a|^2

__device__ __forceinline__ float softplusf(float x) {
    return (x > 20.f) ? x : log1pf(__expf(x));
}
__device__ __forceinline__ float sigmoidf(float x) {
    return 1.f / (1.f + __expf(-x));
}
__device__ __forceinline__ void msCombine(float& m, float& s, float m2, float s2) {
    const float mn = fmaxf(m, m2);
    s = s * __expf(m - mn) + s2 * __expf(m2 - mn);
    m = mn;
}

// ---- block reductions for 1024 threads (16 waves), red[16] LDS ----
__device__ __forceinline__ float blockSum1024(float v, float* red) {
    #pragma unroll
    for (int m = 32; m >= 1; m >>= 1) v += __shfl_xor(v, m);
    __syncthreads();
    if ((threadIdx.x & 63) == 0) red[threadIdx.x >> 6] = v;
    __syncthreads();
    float s = 0.f;
    #pragma unroll
    for (int i = 0; i < 16; ++i) s += red[i];
    return s;
}
__device__ __forceinline__ float blockMax1024(float v, float* red) {
    #pragma unroll
    for (int m = 32; m >= 1; m >>= 1) v = fmaxf(v, __shfl_xor(v, m));
    __syncthreads();
    if ((threadIdx.x & 63) == 0) red[threadIdx.x >> 6] = v;
    __syncthreads();
    float s = -1e30f;
    #pragma unroll
    for (int i = 0; i < 16; ++i) s = fmaxf(s, red[i]);
    return s;
}

struct SetupArgs {
    const float *x, *prv, *Wc, *bc;
    const float *Wk_r, *bk_r, *Wb_r, *bb_r, *Wg_r, *bg_r, *Ws_r, *bs_r, *Wgam_r, *bgam_r;
    const float *Wk_w, *bk_w, *Wb_w, *bb_w, *Wg_w, *bg_w, *Ws_w, *bs_w, *Wgam_w, *bgam_w;
    const float *We_w, *be_w, *Wa_w, *ba_w;
    float *ws, *out;
};

// one block per batch: controller GEMM + projections + batched scalar reductions
__global__ __launch_bounds__(256) void k_setup(SetupArgs a) {
    __shared__ float ci[CTRL];
    __shared__ float h[Cc];
    __shared__ alignas(16) float kbuf[128];
    __shared__ alignas(16) float abuf[64];
    __shared__ float red[4][16];
    __shared__ float sums[16];
    const int b = blockIdx.x, t = threadIdx.x;

    if (t < INn)       ci[t] = a.x[b * INn + t];
    else if (t < CTRL) ci[t] = a.prv[b * Dd + (t - INn)];
    __syncthreads();

    float acc = a.bc[t];
    #pragma unroll 16
    for (int i = 0; i < CTRL; ++i) acc += ci[i] * a.Wc[i * Cc + t];
    const float hv = fmaxf(acc, 0.f);
    h[t] = hv;
    a.out[b * OUTW + t] = hv;
    __syncthreads();

    {
        const int job = t >> 6, d = t & 63;
        const float* W  = (job == 0) ? a.Wk_w : (job == 1) ? a.Wk_r : (job == 2) ? a.We_w : a.Wa_w;
        const float* bs = (job == 0) ? a.bk_w : (job == 1) ? a.bk_r : (job == 2) ? a.be_w : a.ba_w;
        float p = bs[d];
        #pragma unroll 16
        for (int c = 0; c < Cc; ++c) p += h[c] * W[c * Dd + d];
        if (job == 0)      { a.ws[OFF_KW + b * Dd + d] = p; kbuf[d] = p; }
        else if (job == 1) { a.ws[OFF_KR + b * Dd + d] = p; kbuf[64 + d] = p; }
        else if (job == 2) { a.ws[OFF_ER + b * Dd + d] = sigmoidf(p); }
        else               { const float ad = tanhf(p); a.ws[OFF_AD + b * Dd + d] = ad; abuf[d] = ad; }
    }
    __syncthreads();

    float v[16];
    v[0] = hv * a.Wb_w[t];  v[1] = hv * a.Wg_w[t];  v[2] = hv * a.Wgam_w[t];
    v[3] = hv * a.Ws_w[t * 3 + 0]; v[4] = hv * a.Ws_w[t * 3 + 1]; v[5] = hv * a.Ws_w[t * 3 + 2];
    v[6] = hv * a.Wb_r[t];  v[7] = hv * a.Wg_r[t];  v[8] = hv * a.Wgam_r[t];
    v[9] = hv * a.Ws_r[t * 3 + 0]; v[10] = hv * a.Ws_r[t * 3 + 1]; v[11] = hv * a.Ws_r[t * 3 + 2];
    v[12] = (t < 64) ? kbuf[t] * kbuf[t] : 0.f;
    v[13] = (t >= 64 && t < 128) ? kbuf[t] * kbuf[t] : 0.f;
    v[14] = (t < 64) ? abuf[t] * kbuf[64 + t] : 0.f;
    v[15] = (t < 64) ? abuf[t] * abuf[t] : 0.f;
    #pragma unroll
    for (int k = 0; k < 16; ++k) {
        #pragma unroll
        for (int m = 32; m >= 1; m >>= 1) v[k] += __shfl_xor(v[k], m);
    }
    if ((t & 63) == 0) {
        #pragma unroll
        for (int k = 0; k < 16; ++k) red[t >> 6][k] = v[k];
    }
    __syncthreads();
    if (t < 16) sums[t] = red[0][t] + red[1][t] + red[2][t] + red[3][t];
    __syncthreads();

    if (t == 0) {
        float* sc = a.ws + OFF_SC + b * 16;
        sc[0] = softplusf(sums[0] + a.bb_w[0]);
        sc[1] = sigmoidf(sums[1] + a.bg_w[0]);
        sc[2] = softplusf(sums[2] + a.bgam_w[0]) + 1.f;
        sc[3] = sqrtf(sums[12]);
        sc[4] = softplusf(sums[6] + a.bb_r[0]);
        sc[5] = sigmoidf(sums[7] + a.bg_r[0]);
        sc[6] = softplusf(sums[8] + a.bgam_r[0]) + 1.f;
        sc[7] = sqrtf(sums[13]);
        {
            const float v0 = sums[3] + a.bs_w[0], v1 = sums[4] + a.bs_w[1], v2 = sums[5] + a.bs_w[2];
            const float m = fmaxf(fmaxf(v0, v1), v2);
            const float e0 = __expf(v0 - m), e1 = __expf(v1 - m), e2 = __expf(v2 - m);
            const float s = e0 + e1 + e2;
            sc[8] = e0 / s; sc[9] = e1 / s; sc[10] = e2 / s;
        }
        sc[11] = sums[14];
        {
            const float v0 = sums[9] + a.bs_r[0], v1 = sums[10] + a.bs_r[1], v2 = sums[11] + a.bs_r[2];
            const float m = fmaxf(fmaxf(v0, v1), v2);
            const float e0 = __expf(v0 - m), e1 = __expf(v1 - m), e2 = __expf(v2 - m);
            const float s = e0 + e1 + e2;
            sc[12] = e0 / s; sc[13] = e1 / s; sc[14] = e2 / s;
        }
        sc[15] = sums[15];
    }
}

// streaming pass (best-known): 4096 blocks, one 32-row tile per wave.
// Register accumulation -> [32][49] LDS transpose -> 2 lanes/row finalize
// -> dense SoA stores + per-block online {M,S}.
__global__ __launch_bounds__(256) void k_pass1(const float* __restrict__ mem,
                                               float* __restrict__ ws) {
    __shared__ float tr[4][32 * 49];
    __shared__ float wm[4], wsum[4];
    const int t = threadIdx.x;
    const int wv = t >> 6, lane = t & 63;
    const int cg = lane & 7;
    const int rr = lane >> 3;
    const int tile = (blockIdx.x << 2) + wv;
    const int rowbase = tile << 5;
    const int b = rowbase >> 13;
    const int cb = cg << 3;

    const float4 kwA = *(const float4*)(ws + OFF_KW + (b << 6) + cb);
    const float4 kwB = *(const float4*)(ws + OFF_KW + (b << 6) + cb + 4);
    const float4 krA = *(const float4*)(ws + OFF_KR + (b << 6) + cb);
    const float4 krB = *(const float4*)(ws + OFF_KR + (b << 6) + cb + 4);
    const float4 evA = *(const float4*)(ws + OFF_ER + (b << 6) + cb);
    const float4 evB = *(const float4*)(ws + OFF_ER + (b << 6) + cb + 4);
    const float4 avA = *(const float4*)(ws + OFF_AD + (b << 6) + cb);
    const float4 avB = *(const float4*)(ws + OFF_AD + (b << 6) + cb + 4);
    const float beta = ws[OFF_SC + b * 16 + 0];
    const float kn   = ws[OFF_SC + b * 16 + 3];

    float acc[4][6];
    #pragma unroll
    for (int s = 0; s < 4; ++s) {
        const int row = rowbase + (s << 3) + rr;
        const float* mp = mem + ((size_t)row << 6) + cb;
        const float4 m0 = *(const float4*)(mp);
        const float4 m1 = *(const float4*)(mp + 4);
        float dw = 0.f, dr = 0.f, nq = 0.f, e1 = 0.f, e2 = 0.f, c5 = 0.f;
        #define ACC(mv, kwv, krv, evv, avv) { \
            const float me = (mv) * (evv); \
            dw = fmaf((mv), (kwv), dw); \
            dr = fmaf((mv), (krv), dr); \
            nq = fmaf((mv), (mv), nq); \
            e1 = fmaf((mv), (avv) - me, e1); \
            e2 = fmaf(me, fmaf(-2.f, (avv), me), e2); \
            c5 = fmaf(me, (krv), c5); }
        ACC(m0.x, kwA.x, krA.x, evA.x, avA.x)
        ACC(m0.y, kwA.y, krA.y, evA.y, avA.y)
        ACC(m0.z, kwA.z, krA.z, evA.z, avA.z)
        ACC(m0.w, kwA.w, krA.w, evA.w, avA.w)
        ACC(m1.x, kwB.x, krB.x, evB.x, avB.x)
        ACC(m1.y, kwB.y, krB.y, evB.y, avB.y)
        ACC(m1.z, kwB.z, krB.z, evB.z, avB.z)
        ACC(m1.w, kwB.w, krB.w, evB.w, avB.w)
        #undef ACC
        acc[s][0] = dw; acc[s][1] = dr; acc[s][2] = nq;
        acc[s][3] = e1; acc[s][4] = e2; acc[s][5] = c5;
    }

    float* T = tr[wv];
    #pragma unroll
    for (int s = 0; s < 4; ++s) {
        #pragma unroll
        for (int v = 0; v < 6; ++v)
            T[((s << 3) + rr) * 49 + cg * 6 + v] = acc[s][v];
    }
    __syncthreads();

    const int rd = lane & 31;
    const int gb = (lane >> 5) << 2;
    float dw = 0.f, dr = 0.f, nq = 0.f, e1 = 0.f, e2 = 0.f, c5 = 0.f;
    #pragma unroll
    for (int g = 0; g < 4; ++g) {
        const float* p = T + rd * 49 + (gb + g) * 6;
        dw += p[0]; dr += p[1]; nq += p[2];
        e1 += p[3]; e2 += p[4]; c5 += p[5];
    }
    dw += __shfl_xor(dw, 32); dr += __shfl_xor(dr, 32); nq += __shfl_xor(nq, 32);
    e1 += __shfl_xor(e1, 32); e2 += __shfl_xor(e2, 32); c5 += __shfl_xor(c5, 32);

    const int row = rowbase + rd;
    const float xw = beta * dw / (sqrtf(nq) * kn + EPSF);
    if (lane < 32) {
        ws[OFF_XW + row] = xw;
        float4 p4; p4.x = dr; p4.y = c5; p4.z = nq; p4.w = e1;
        *(float4*)(ws + OFF_P4 + ((size_t)row << 2)) = p4;
        ws[OFF_E2 + row] = e2;
    }

    float om = xw, os = 1.f;
    #pragma unroll
    for (int mk = 1; mk <= 32; mk <<= 1) {
        const float m2 = __shfl_xor(om, mk), s2 = __shfl_xor(os, mk);
        msCombine(om, os, m2, s2);
    }
    if (lane == 0) { wm[wv] = om; wsum[wv] = os; }
    __syncthreads();
    if (t == 0) {
        float M = wm[0], S = wsum[0];
        msCombine(M, S, wm[1], wsum[1]);
        msCombine(M, S, wm[2], wsum[2]);
        msCombine(M, S, wm[3], wsum[3]);
        ws[OFF_MS + (blockIdx.x << 1)]     = M;
        ws[OFF_MS + (blockIdx.x << 1) + 1] = S * 0.5f;
    }
}

// fused W+R addressing: one block (1024 thr) per batch; thread t owns rows [8t,8t+8).
// Stores NORMALIZED WPW / WPR.
__global__ __launch_bounds__(1024, 4) void k_addrBoth(float* __restrict__ ws,
                                                      const float* __restrict__ prevw_w,
                                                      const float* __restrict__ prevw_r) {
    __shared__ float buf[Nn];
    __shared__ float red[16];
    __shared__ float sMS[2];
    const int b = blockIdx.x, t = threadIdx.x;
    const int bN = b * Nn;
    const int base = t << 3;
    const float* sc = ws + OFF_SC + b * 16;
    const float g_w = sc[1], gam_w = sc[2];
    const float s0w = sc[8], s1w = sc[9], s2w = sc[10];
    const float beta_r = sc[4], g_r = sc[5], gam_r = sc[6], kn_r = sc[7];
    const float AK = sc[11], A2 = sc[15];
    const float s0r = sc[12], s1r = sc[13], s2r = sc[14];

    // combine the 64 per-pass1-block {M,S} pairs of this batch
    if (t < 64) {
        float m = ws[OFF_MS + ((b * 64 + t) << 1)];
        float s = ws[OFF_MS + ((b * 64 + t) << 1) + 1];
        #pragma unroll
        for (int mk = 1; mk <= 32; mk <<= 1) {
            const float m2 = __shfl_xor(m, mk), s2 = __shfl_xor(s, mk);
            msCombine(m, s, m2, s2);
        }
        if (t == 0) { sMS[0] = m; sMS[1] = 1.f / s; }
    }

    // ---- prefetch all per-row data (hides latency under W side) ----
    const float4 xw0 = *(const float4*)(ws + OFF_XW + bN + base);
    const float4 xw1 = *(const float4*)(ws + OFF_XW + bN + base + 4);
    const float4 pw0 = *(const float4*)(prevw_w + bN + base);
    const float4 pw1 = *(const float4*)(prevw_w + bN + base + 4);
    float4 p4[8];
    #pragma unroll
    for (int i = 0; i < 8; ++i)
        p4[i] = *(const float4*)(ws + OFF_P4 + ((size_t)(bN + base + i) << 2));
    const float4 e20 = *(const float4*)(ws + OFF_E2 + bN + base);
    const float4 e21 = *(const float4*)(ws + OFF_E2 + bN + base + 4);
    const float4 pr0 = *(const float4*)(prevw_r + bN + base);
    const float4 pr1 = *(const float4*)(prevw_r + bN + base + 4);
    __syncthreads();           // sMS ready
    const float M = sMS[0], invS = sMS[1];

    // ---------- W side ----------
    float xs[8] = {xw0.x, xw0.y, xw0.z, xw0.w, xw1.x, xw1.y, xw1.z, xw1.w};
    float pw[8] = {pw0.x, pw0.y, pw0.z, pw0.w, pw1.x, pw1.y, pw1.z, pw1.w};
    #pragma unroll
    for (int i = 0; i < 8; ++i)
        buf[base + i] = g_w * __expf(xs[i] - M) * invS + (1.f - g_w) * pw[i];
    __syncthreads();
    {
        float nb[10];
        nb[0] = buf[(base + Nn - 1) & (Nn - 1)];
        #pragma unroll
        for (int i = 0; i < 8; ++i) nb[i + 1] = buf[base + i];
        nb[9] = buf[(base + 8) & (Nn - 1)];
        float lps = 0.f;
        #pragma unroll
        for (int i = 0; i < 8; ++i) {
            const float wsv = s0w * nb[i + 2] + s1w * nb[i + 1] + s2w * nb[i];
            const float wp = __expf(gam_w * __logf(wsv));
            xs[i] = wp; lps += wp;
        }
        const float PS = blockSum1024(lps, red);
        const float pinv = 1.f / (PS + EPSF);
        #pragma unroll
        for (int i = 0; i < 8; ++i) xs[i] *= pinv;     // normalized ww
    }
    {
        float4 w0, w1;
        w0.x = xs[0]; w0.y = xs[1]; w0.z = xs[2]; w0.w = xs[3];
        w1.x = xs[4]; w1.y = xs[5]; w1.z = xs[6]; w1.w = xs[7];
        *(float4*)(ws + OFF_WPW + bN + base) = w0;
        *(float4*)(ws + OFF_WPW + bN + base + 4) = w1;
    }

    // ---------- R side ----------
    const float e2a[8] = {e20.x, e20.y, e20.z, e20.w, e21.x, e21.y, e21.z, e21.w};
    float lmax = -1e30f;
    #pragma unroll
    for (int i = 0; i < 8; ++i) {
        const float w = xs[i];
        const float d = p4[i].x + w * (AK - p4[i].y);              // dr, c5
        float qq = p4[i].z + 2.f * w * p4[i].w + w * w * (e2a[i] + A2);  // nq, e1
        qq = fmaxf(qq, 0.f);
        const float x = beta_r * d / (sqrtf(qq) * kn_r + EPSF);
        xs[i] = x; lmax = fmaxf(lmax, x);
    }
    const float Mr = blockMax1024(lmax, red);
    float lsr = 0.f;
    #pragma unroll
    for (int i = 0; i < 8; ++i) { const float e = __expf(xs[i] - Mr); xs[i] = e; lsr += e; }
    const float Sr = blockSum1024(lsr, red);
    const float srinv = 1.f / Sr;
    const float prv8[8] = {pr0.x, pr0.y, pr0.z, pr0.w, pr1.x, pr1.y, pr1.z, pr1.w};
    __syncthreads();            // all W-side buf reads complete
    #pragma unroll
    for (int i = 0; i < 8; ++i)
        buf[base + i] = g_r * xs[i] * srinv + (1.f - g_r) * prv8[i];
    __syncthreads();
    {
        float nb[10];
        nb[0] = buf[(base + Nn - 1) & (Nn - 1)];
        #pragma unroll
        for (int i = 0; i < 8; ++i) nb[i + 1] = buf[base + i];
        nb[9] = buf[(base + 8) & (Nn - 1)];
        float lpr = 0.f;
        #pragma unroll
        for (int i = 0; i < 8; ++i) {
            const float wsv = s0r * nb[i + 2] + s1r * nb[i + 1] + s2r * nb[i];
            const float wp = __expf(gam_r * __logf(wsv));
            xs[i] = wp; lpr += wp;
        }
        const float PSr = blockSum1024(lpr, red);
        const float prinv = 1.f / (PSr + EPSF);
        float4 w0, w1;
        w0.x = xs[0] * prinv; w0.y = xs[1] * prinv; w0.z = xs[2] * prinv; w0.w = xs[3] * prinv;
        w1.x = xs[4] * prinv; w1.y = xs[5] * prinv; w1.z = xs[6] * prinv; w1.w = xs[7] * prinv;
        *(float4*)(ws + OFF_WPR + bN + base) = w0;
        *(float4*)(ws + OFF_WPR + bN + base + 4) = w1;
    }
}

// read-vector partials: recompute new_mem on the fly (second & last mem pass)
__global__ __launch_bounds__(256) void k_read(const float* __restrict__ mem,
                                              float* __restrict__ ws) {
    __shared__ float lds[4 * 64];
    const int b = blockIdx.x >> 5;
    const int chunk = blockIdx.x & 31;
    const int t = threadIdx.x;
    const int lane = t & 63, wv = t >> 6;
    const int q = lane & 15, r = lane >> 4;

    const float4 evv = *(const float4*)(ws + OFF_ER + (b << 6) + (q << 2));
    const float4 avv = *(const float4*)(ws + OFF_AD + (b << 6) + (q << 2));
    float a0 = 0.f, a1 = 0.f, a2 = 0.f, a3 = 0.f;
    const int base_n = chunk << 8;
    #pragma unroll 4
    for (int gi = wv; gi < 64; gi += 4) {
        const int n = base_n + (gi << 2) + r;
        const int row = b * Nn + n;
        const float4 mv = *(const float4*)(mem + ((size_t)row << 6) + (q << 2));
        const float w   = ws[OFF_WPW + row];
        const float wrv = ws[OFF_WPR + row];
        a0 = fmaf((mv.x * (1.f - w * evv.x) + w * avv.x), wrv, a0);
        a1 = fmaf((mv.y * (1.f - w * evv.y) + w * avv.y), wrv, a1);
        a2 = fmaf((mv.z * (1.f - w * evv.z) + w * avv.z), wrv, a2);
        a3 = fmaf((mv.w * (1.f - w * evv.w) + w * avv.w), wrv, a3);
    }
    #pragma unroll
    for (int m = 16; m <= 32; m <<= 1) {
        a0 += __shfl_xor(a0, m); a1 += __shfl_xor(a1, m);
        a2 += __shfl_xor(a2, m); a3 += __shfl_xor(a3, m);
    }
    if (r == 0) {
        lds[wv * 64 + q * 4 + 0] = a0; lds[wv * 64 + q * 4 + 1] = a1;
        lds[wv * 64 + q * 4 + 2] = a2; lds[wv * 64 + q * 4 + 3] = a3;
    }
    __syncthreads();
    if (t < 64) {
        ws[OFF_PT + blockIdx.x * 64 + t] = lds[t] + lds[64 + t] + lds[128 + t] + lds[192 + t];
    }
}

__global__ __launch_bounds__(64) void k_reduce(const float* __restrict__ ws,
                                               float* __restrict__ out) {
    const int b = blockIdx.x, d = threadIdx.x;
    float s = 0.f;
    #pragma unroll
    for (int i = 0; i < 32; ++i) s += ws[OFF_PT + ((b << 5) + i) * 64 + d];
    out[b * OUTW + 256 + d] = s;
}

extern "C" void kernel_launch(void* const* d_in, const int* in_sizes, int n_in,
                              void* d_out, int out_size, void* d_ws, size_t ws_size,
                              hipStream_t stream) {
    const float* x      = (const float*)d_in[0];
    const float* mem    = (const float*)d_in[1];
    const float* prw_r  = (const float*)d_in[2];
    const float* prw_w  = (const float*)d_in[3];
    const float* prv    = (const float*)d_in[4];

    float* ws  = (float*)d_ws;
    float* out = (float*)d_out;

    SetupArgs a;
    a.x = x; a.prv = prv;
    a.Wc = (const float*)d_in[5];  a.bc = (const float*)d_in[6];
    a.Wk_r = (const float*)d_in[7];  a.bk_r = (const float*)d_in[8];
    a.Wb_r = (const float*)d_in[9];  a.bb_r = (const float*)d_in[10];
    a.Wg_r = (const float*)d_in[11]; a.bg_r = (const float*)d_in[12];
    a.Ws_r = (const float*)d_in[13]; a.bs_r = (const float*)d_in[14];
    a.Wgam_r = (const float*)d_in[15]; a.bgam_r = (const float*)d_in[16];
    a.Wk_w = (const float*)d_in[17]; a.bk_w = (const float*)d_in[18];
    a.Wb_w = (const float*)d_in[19]; a.bb_w = (const float*)d_in[20];
    a.Wg_w = (const float*)d_in[21]; a.bg_w = (const float*)d_in[22];
    a.Ws_w = (const float*)d_in[23]; a.bs_w = (const float*)d_in[24];
    a.Wgam_w = (const float*)d_in[25]; a.bgam_w = (const float*)d_in[26];
    a.We_w = (const float*)d_in[27]; a.be_w = (const float*)d_in[28];
    a.Wa_w = (const float*)d_in[29]; a.ba_w = (const float*)d_in[30];
    a.ws = ws; a.out = out;

    k_setup   <<<Bb,   256,  0, stream>>>(a);
    k_pass1   <<<4096, 256,  0, stream>>>(mem, ws);
    k_addrBoth<<<Bb,   1024, 0, stream>>>(ws, prw_w, prw_r);
    k_read    <<<2048, 256,  0, stream>>>(mem, ws);
    k_reduce  <<<Bb,   64,   0, stream>>>(ws, out);
}